// Round 10
// baseline (263.818 us; speedup 1.0000x reference)
//
// Round 10: k0 eliminated — GEMM blocks self-derive W/W2 fragments from raw
// weights (pack permutation + 10-FMA einsum inline); cnt zeroed by memset.
// Pipeline: hipMemsetAsync(cnt) -> k2 (GEMM || scatter) -> k4.
#include <hip/hip_runtime.h>
#include <hip/hip_bf16.h>

#define N_NODES 25000
#define N_EDGES 320000
#define F 64
#define H 5
#define R 20
#define B 10
#define HF 320            // H*F
#define GEMMB 391         // 64-row GEMM blocks (512 threads, 8 waves)
#define SCATB 625         // edge-scatter blocks (512 threads): 625*512 = 320000
#define MPAD 25024        // 391*64 rows
#define CAP 64            // bucket capacity per dst (Poisson(12.8): P(deg>64) ~ 1e-8)

typedef __attribute__((ext_vector_type(8))) short short8;
typedef __attribute__((ext_vector_type(4))) short short4v;
typedef __attribute__((ext_vector_type(4))) float float4v;

__device__ __forceinline__ float ldf(const void* p, int f32, int i) {
    if (f32) return ((const float*)p)[i];
    else     return __bfloat162float(((const __hip_bfloat16*)p)[i]);
}
__device__ __forceinline__ int ldi(const void* p, int i64, int i) {
    if (i64) return ((const int*)p)[2 * i];
    else     return ((const int*)p)[i];
}
__device__ __forceinline__ float b2f(unsigned short u) {
    union { unsigned u32; float f; } v; v.u32 = ((unsigned)u) << 16; return v.f;
}
__device__ __forceinline__ short f2bs(float x) {
    __hip_bfloat16 v = __float2bfloat16(x); return *(short*)&v;
}

// ---- inline dtype probes (wave-uniform; call with all lanes active)
__device__ __forceinline__ int probe_f32(const void* feat_raw) {
    unsigned w = ((const unsigned*)feat_raw)[threadIdx.x & 63];
    unsigned e = (w >> 7) & 0xFF;                    // bf16 exponent of low half
    unsigned long long m = __ballot(e >= 110 && e <= 140);
    return __popcll(m) < 32;                         // scattered exponents => fp32
}
__device__ __forceinline__ int probe_i64(const void* src_raw) {
    unsigned v = ((const unsigned*)src_raw)[2 * (threadIdx.x & 63) + 1];
    unsigned long long m = __ballot(v == 0);
    return __popcll(m) > 32;                         // odd words all zero => int64
}

// ---- in-block weight-fragment derivation (replaces k0's Wpack/W2pack).
// Fragment element (t, q, lane, j) == Wpack[((t*2+q)*64+lane)*8+j] of the old
// pack: k = (q?32:0)+((lane>>4)<<3)+j, c = t*16+(lane&15).
__device__ __forceinline__ short8 packW(const void* sfw, const void* fcw,
                                        int f32, int t, int q, int lane) {
    short8 w;
    const int col = lane & 15;
    const int kb = (q ? 32 : 0) + ((lane >> 4) << 3);
#pragma unroll
    for (int j = 0; j < 8; ++j) {
        const int k = kb + j;
        float v = (t < 20) ? ldf(sfw, f32, k * HF + t * 16 + col)
                           : ldf(fcw, f32, k * F + (t - 20) * 16 + col);
        w[j] = f2bs(v);
    }
    return w;
}
// W2 fragment: c = t*16+col -> relation r = t, part = (col>>3)&1, h = col&7;
// element = sum_b wc[t*B+b] * aw[b*(2F*H) + (part*F+k)*H + h]  (0 if h >= H).
__device__ __forceinline__ short8 packW2(const void* aw, const void* wc,
                                         int f32, int t, int q, int lane) {
    short8 w;
    const int col = lane & 15;
    const int part = (col >> 3) & 1, h = col & 7;
    const int kb = (q ? 32 : 0) + ((lane >> 4) << 3);
#pragma unroll
    for (int j = 0; j < 8; ++j) {
        const int k = kb + j;
        float acc = 0.f;
        if (h < H) {
#pragma unroll
            for (int bb = 0; bb < B; ++bb)
                acc += ldf(wc, f32, t * B + bb) *
                       ldf(aw, f32, bb * (2 * F * H) + (part * F + k) * H + h);
        }
        w[j] = f2bs(acc);
    }
    return w;
}

// ---------------- K2: GEMM (blocks 0..GEMMB-1, 512 threads = 8 waves, 64 rows,
// self-contained weight derivation) || edge scatter (blocks GEMMB..).
// Wave (wv = w&3, gh = w>>2) handles t-tiles wv*5+tt for row-groups {gh*2,gh*2+1}.
__global__ __launch_bounds__(512) void k2_gemm(const void* __restrict__ feat,
                                               const void* __restrict__ srcp,
                                               const void* __restrict__ dstp,
                                               const void* __restrict__ etp,
                                               const void* __restrict__ fcw,
                                               const void* __restrict__ sfw,
                                               const void* __restrict__ aw,
                                               const void* __restrict__ wc,
                                               __hip_bfloat16* __restrict__ selfz,
                                               __hip_bfloat16* __restrict__ zc,
                                               __hip_bfloat16* __restrict__ a_src,
                                               __hip_bfloat16* __restrict__ a_dst,
                                               int* __restrict__ cnt,
                                               unsigned* __restrict__ perm) {
    __shared__ short zl[64][66];
    const int tid = threadIdx.x;

    if (blockIdx.x >= GEMMB) {
        // ---- edge scatter into fixed-capacity buckets
        const int i64 = probe_i64(srcp);
        const int e = (blockIdx.x - GEMMB) * 512 + tid;
        if (e < N_EDGES) {
            int d = ldi(dstp, i64, e);
            int s = ldi(srcp, i64, e);
            int r = ldi(etp, i64, e);
            int pos = atomicAdd(&cnt[d], 1);
            if (pos < CAP) perm[d * CAP + pos] = ((unsigned)r << 16) | (unsigned)s;
        }
        return;
    }

    const int f32 = probe_f32(feat);
    const int wave = tid >> 6, lane = tid & 63;
    const int quad = lane >> 4, col = lane & 15;
    const int wv = wave & 3, gh = wave >> 2;     // t-slot / row-group half
    const int r0 = blockIdx.x * 64;

    // A fragments for this wave's 2 row-groups (f32 converted in-register)
    short8 a0g[2], a1g[2];
#pragma unroll
    for (int gg = 0; gg < 2; ++gg) {
        const int g = gh * 2 + gg;
        int am = r0 + g * 16 + col;
        if (am >= N_NODES) am = N_NODES - 1;
        if (f32) {
            const float* Af = (const float*)feat;
            float4v f0 = *(const float4v*)(Af + am * F + quad * 8);
            float4v f1 = *(const float4v*)(Af + am * F + quad * 8 + 4);
            float4v g0 = *(const float4v*)(Af + am * F + 32 + quad * 8);
            float4v g1 = *(const float4v*)(Af + am * F + 32 + quad * 8 + 4);
#pragma unroll
            for (int j = 0; j < 4; ++j) {
                a0g[gg][j] = f2bs(f0[j]); a0g[gg][j + 4] = f2bs(f1[j]);
                a1g[gg][j] = f2bs(g0[j]); a1g[gg][j + 4] = f2bs(g1[j]);
            }
        } else {
            const __hip_bfloat16* A = (const __hip_bfloat16*)feat;
            a0g[gg] = *(const short8*)(A + am * F + quad * 8);
            a1g[gg] = *(const short8*)(A + am * F + 32 + quad * 8);
        }
    }

    // ---- zc tile (t = 20 + wv): W derived in-block, 2 row-groups
    {
        const int t = 20 + wv;
        short8 b0 = packW(sfw, fcw, f32, t, 0, lane);
        short8 b1 = packW(sfw, fcw, f32, t, 1, lane);
        const int cb = wv * 16 + quad * 4;
#pragma unroll
        for (int gg = 0; gg < 2; ++gg) {
            const int g = gh * 2 + gg;
            float4v acc = {0.f, 0.f, 0.f, 0.f};
            acc = __builtin_amdgcn_mfma_f32_16x16x32_bf16(b0, a0g[gg], acc, 0, 0, 0);
            acc = __builtin_amdgcn_mfma_f32_16x16x32_bf16(b1, a1g[gg], acc, 0, 0, 0);
            short4v pv;
#pragma unroll
            for (int j = 0; j < 4; ++j) pv[j] = f2bs(acc[j]);
            const int row = r0 + g * 16 + col;
            *(short4v*)(zc + row * F + cb) = pv;
            *(short4v*)&zl[g * 16 + col][cb] = pv;
        }
    }
    __syncthreads();

    // ---- GEMM2 A-side (zc^T): zl[m][k] for this wave's 2 row-groups
    short8 c0g[2], c1g[2];
#pragma unroll
    for (int gg = 0; gg < 2; ++gg) {
        const int g = gh * 2 + gg;
        c0g[gg] = *(const short8*)&zl[g * 16 + col][quad * 8];
        c1g[gg] = *(const short8*)&zl[g * 16 + col][32 + quad * 8];
    }

    // ---- selfz tiles (t = wv*5 .. +4): W derived once, 2 groups
#pragma unroll
    for (int tt = 0; tt < 5; ++tt) {
        const int t = wv * 5 + tt;
        short8 b0 = packW(sfw, fcw, f32, t, 0, lane);
        short8 b1 = packW(sfw, fcw, f32, t, 1, lane);
#pragma unroll
        for (int gg = 0; gg < 2; ++gg) {
            const int g = gh * 2 + gg;
            float4v acc = {0.f, 0.f, 0.f, 0.f};
            acc = __builtin_amdgcn_mfma_f32_16x16x32_bf16(b0, a0g[gg], acc, 0, 0, 0);
            acc = __builtin_amdgcn_mfma_f32_16x16x32_bf16(b1, a1g[gg], acc, 0, 0, 0);
            short4v pv;
#pragma unroll
            for (int j = 0; j < 4; ++j) pv[j] = f2bs(acc[j]);
            const int row = r0 + g * 16 + col;
            *(short4v*)(selfz + row * HF + t * 16 + quad * 4) = pv;
        }
    }

    // ---- GEMM2 tiles (basis-einsum W2 derived in-block) -> a_src / a_dst
    __hip_bfloat16* dsta = (quad & 2) ? a_dst : a_src;
    const int hoff = (quad & 1) * 4;
#pragma unroll
    for (int tt = 0; tt < 5; ++tt) {
        const int t = wv * 5 + tt;
        short8 b0 = packW2(aw, wc, f32, t, 0, lane);
        short8 b1 = packW2(aw, wc, f32, t, 1, lane);
#pragma unroll
        for (int gg = 0; gg < 2; ++gg) {
            const int g = gh * 2 + gg;
            float4v acc = {0.f, 0.f, 0.f, 0.f};
            acc = __builtin_amdgcn_mfma_f32_16x16x32_bf16(b0, c0g[gg], acc, 0, 0, 0);
            acc = __builtin_amdgcn_mfma_f32_16x16x32_bf16(b1, c1g[gg], acc, 0, 0, 0);
            short4v pv;
#pragma unroll
            for (int j = 0; j < 4; ++j) pv[j] = f2bs(acc[j]);
            const int row = r0 + g * 16 + col;
            *(short4v*)(dsta + row * 160 + t * 8 + hoff) = pv;
        }
    }
}

// ---------------- K4 (round-9 exact): one wave per dst — register-resident,
// no LDS/syncthreads; 4-deep edge batching; per-edge state via shfl.
__global__ __launch_bounds__(256, 8) void k4_agg(const void* __restrict__ feat_raw,
                                                 const __hip_bfloat16* __restrict__ selfz,
                                                 const unsigned short* __restrict__ zc,
                                                 const __hip_bfloat16* __restrict__ a_src,
                                                 const __hip_bfloat16* __restrict__ a_dst,
                                                 const int* __restrict__ cnt,
                                                 const unsigned* __restrict__ perm,
                                                 void* __restrict__ out) {
    const int f32 = probe_f32(feat_raw);
    const int tid = threadIdx.x;
    const int wid = tid >> 6, lane = tid & 63;
    const int d = blockIdx.x * 4 + wid;       // 6250*4 = 25000

    // gate loads first: edge list + degree
    const unsigned pk = perm[d * CAP + lane];
    int n = cnt[d];
    if (n > CAP) n = CAP;
    const int s_l = (int)(pk & 0xFFFFu), r_l = (int)(pk >> 16);

    const short* as = (const short*)a_src;
    const short* ad = (const short*)a_dst;

    // ---- phase A: lane e computes its edge's 5 leaky-relu logits (registers only)
    float av0 = 0.f, av1 = 0.f, av2 = 0.f, av3 = 0.f, av4 = 0.f;
    if (lane < n) {
        short8 sv = *(const short8*)(as + s_l * 160 + r_l * 8);
        short8 dv = *(const short8*)(ad + d * 160 + r_l * 8);   // one hot row/wave
        float t0 = b2f((unsigned short)sv[0]) + b2f((unsigned short)dv[0]);
        float t1 = b2f((unsigned short)sv[1]) + b2f((unsigned short)dv[1]);
        float t2 = b2f((unsigned short)sv[2]) + b2f((unsigned short)dv[2]);
        float t3 = b2f((unsigned short)sv[3]) + b2f((unsigned short)dv[3]);
        float t4 = b2f((unsigned short)sv[4]) + b2f((unsigned short)dv[4]);
        av0 = fmaxf(t0, 0.01f * t0);
        av1 = fmaxf(t1, 0.01f * t1);
        av2 = fmaxf(t2, 0.01f * t2);
        av3 = fmaxf(t3, 0.01f * t3);
        av4 = fmaxf(t4, 0.01f * t4);
    }

    // ---- phase B: 64 feature-lanes accumulate; per-edge state via shfl
    float acc[H] = {0.f, 0.f, 0.f, 0.f, 0.f};
    int e = 0;
    for (; e + 4 <= n; e += 4) {
        int s_[4];
#pragma unroll
        for (int u = 0; u < 4; ++u) s_[u] = __shfl(s_l, e + u);
        float zs[4];
#pragma unroll
        for (int u = 0; u < 4; ++u) zs[u] = b2f(zc[s_[u] * F + lane]);
#pragma unroll
        for (int u = 0; u < 4; ++u) {
            acc[0] += __shfl(av0, e + u) * zs[u];
            acc[1] += __shfl(av1, e + u) * zs[u];
            acc[2] += __shfl(av2, e + u) * zs[u];
            acc[3] += __shfl(av3, e + u) * zs[u];
            acc[4] += __shfl(av4, e + u) * zs[u];
        }
    }
    for (; e < n; ++e) {
        int s = __shfl(s_l, e);
        float zs = b2f(zc[s * F + lane]);
        acc[0] += __shfl(av0, e) * zs;
        acc[1] += __shfl(av1, e) * zs;
        acc[2] += __shfl(av2, e) * zs;
        acc[3] += __shfl(av3, e) * zs;
        acc[4] += __shfl(av4, e) * zs;
    }

    const int ob = d * HF + lane;
    if (f32) {
        float* o = (float*)out;
#pragma unroll
        for (int h = 0; h < H; ++h)
            o[ob + h * F] = acc[h] + __bfloat162float(selfz[ob + h * F]);
    } else {
        __hip_bfloat16* o = (__hip_bfloat16*)out;
#pragma unroll
        for (int h = 0; h < H; ++h)
            o[ob + h * F] = __float2bfloat16(acc[h] + __bfloat162float(selfz[ob + h * F]));
    }
}

extern "C" void kernel_launch(void* const* d_in, const int* in_sizes, int n_in,
                              void* d_out, int out_size, void* d_ws, size_t ws_size,
                              hipStream_t stream) {
    const void* feat = d_in[0];
    const void* src  = d_in[1];
    const void* dst  = d_in[2];
    const void* et   = d_in[3];
    const void* fcw  = d_in[4];
    const void* sfw  = d_in[5];
    const void* aw   = d_in[6];
    const void* wc   = d_in[7];

    // ws (~42 MB): selfz | zc | a_src | a_dst | perm | cnt
    char* w = (char*)d_ws;
    __hip_bfloat16* selfz  = (__hip_bfloat16*)w;  w += (size_t)MPAD * HF * 2;
    __hip_bfloat16* zc     = (__hip_bfloat16*)w;  w += (size_t)MPAD * F * 2;
    __hip_bfloat16* a_src  = (__hip_bfloat16*)w;  w += (size_t)MPAD * 160 * 2;
    __hip_bfloat16* a_dst  = (__hip_bfloat16*)w;  w += (size_t)MPAD * 160 * 2;
    unsigned* perm = (unsigned*)w;                w += (size_t)N_NODES * CAP * 4;
    int* cnt       = (int*)w;

    // 2 kernel dispatches + 1 tiny fill: memset(cnt) -> gemm||scatter -> aggregate
    hipMemsetAsync(cnt, 0, (size_t)N_NODES * 4, stream);
    k2_gemm<<<GEMMB + SCATB, 512, 0, stream>>>(feat, src, dst, et, fcw, sfw, aw, wc,
                                               selfz, zc, a_src, a_dst, cnt, perm);
    k4_agg<<<N_NODES / 4, 256, 0, stream>>>(feat, selfz, (const unsigned short*)zc,
                                            a_src, a_dst, cnt, perm, d_out);
}

// Round 11
// 134.208 us; speedup vs baseline: 1.9657x; 1.9657x over previous
//
// Round 11: exact revert to the round-2 configuration — the session's best
// measured result (134.8 us). R10's in-block weight derivation regressed 2x
// (scalar uncoalesced packW/packW2 gathers x391 blocks, VGPR 56->108).
#include <hip/hip_runtime.h>
#include <hip/hip_bf16.h>

#define N_NODES 25000
#define N_EDGES 320000
#define F 64
#define H 5
#define R 20
#define B 10
#define HF 320            // H*F
#define GEMMB 391         // 64-row GEMM blocks
#define MPAD 25024        // 391*64 rows
#define CAP 64            // bucket capacity per dst (Poisson(12.8): P(deg>64) ~ 1e-8)

typedef __attribute__((ext_vector_type(8))) short short8;
typedef __attribute__((ext_vector_type(4))) short short4v;
typedef __attribute__((ext_vector_type(4))) float float4v;
typedef __attribute__((ext_vector_type(2))) float float2v;

__device__ __forceinline__ float ldf(const void* p, int f32, int i) {
    if (f32) return ((const float*)p)[i];
    else     return __bfloat162float(((const __hip_bfloat16*)p)[i]);
}
__device__ __forceinline__ int ldi(const void* p, int i64, int i) {
    if (i64) return ((const int*)p)[2 * i];
    else     return ((const int*)p)[i];
}
__device__ __forceinline__ float b2f(unsigned short u) {
    union { unsigned u32; float f; } v; v.u32 = ((unsigned)u) << 16; return v.f;
}
__device__ __forceinline__ short f2bs(float x) {
    __hip_bfloat16 v = __float2bfloat16(x); return *(short*)&v;
}

// ---- inline dtype probes (wave-uniform; call with all lanes active)
__device__ __forceinline__ int probe_f32(const void* feat_raw) {
    unsigned w = ((const unsigned*)feat_raw)[threadIdx.x & 63];
    unsigned e = (w >> 7) & 0xFF;                    // bf16 exponent of low half
    unsigned long long m = __ballot(e >= 110 && e <= 140);
    return __popcll(m) < 32;                         // scattered exponents => fp32
}
__device__ __forceinline__ int probe_i64(const void* src_raw) {
    unsigned v = ((const unsigned*)src_raw)[2 * (threadIdx.x & 63) + 1];
    unsigned long long m = __ballot(v == 0);
    return __popcll(m) > 32;                         // odd words all zero => int64
}

// ---------------- K0: blocks 0..175 pack weights; blocks 176.. zero cnt
__global__ void k0_setup(const void* __restrict__ feat,
                         const void* __restrict__ fcw, const void* __restrict__ sfw,
                         const void* __restrict__ aw, const void* __restrict__ wc,
                         __hip_bfloat16* __restrict__ Wpack,
                         __hip_bfloat16* __restrict__ W2pack,
                         int* __restrict__ cnt) {
    const int f32 = probe_f32(feat);
    const int b = blockIdx.x, tid = threadIdx.x;
    if (b < 176) {
        const int idx = b * 256 + tid;
        if (idx < 24576) {
            int j = idx & 7, lane = (idx >> 3) & 63, fq = idx >> 9;
            int q = fq & 1, t = fq >> 1;
            int k = (q ? 32 : 0) + ((lane >> 4) << 3) + j;
            int c = t * 16 + (lane & 15);
            float v = (c < HF) ? ldf(sfw, f32, k * HF + c) : ldf(fcw, f32, k * F + (c - HF));
            Wpack[idx] = __float2bfloat16(v);
        } else if (idx < 24576 + 20480) {
            int id2 = idx - 24576;
            int j = id2 & 7, lane = (id2 >> 3) & 63, fq = id2 >> 9;
            int q = fq & 1, t = fq >> 1;
            int k = (q ? 32 : 0) + ((lane >> 4) << 3) + j;
            int c = t * 16 + (lane & 15);
            int r = c >> 4, part = (c >> 3) & 1, h = c & 7;
            float acc = 0.f;
            if (h < H) {
#pragma unroll
                for (int bb = 0; bb < B; ++bb)
                    acc += ldf(wc, f32, r * B + bb) *
                           ldf(aw, f32, bb * (2 * F * H) + (part * F + k) * H + h);
            }
            W2pack[id2] = __float2bfloat16(acc);
        }
    } else {
        const int i = (b - 176) * 256 + tid;
        if (i < N_NODES) cnt[i] = 0;
    }
}

// ---------------- K2: fused GEMM1+GEMM2 (blocks 0..GEMMB-1, 64 rows each)
//                       || edge scatter (blocks GEMMB..)
__global__ __launch_bounds__(256) void k2_gemm(const void* __restrict__ feat,
                                               const void* __restrict__ srcp,
                                               const void* __restrict__ dstp,
                                               const void* __restrict__ etp,
                                               const __hip_bfloat16* __restrict__ Wpack,
                                               const __hip_bfloat16* __restrict__ W2pack,
                                               __hip_bfloat16* __restrict__ selfz,
                                               __hip_bfloat16* __restrict__ zc,
                                               __hip_bfloat16* __restrict__ a_src,
                                               __hip_bfloat16* __restrict__ a_dst,
                                               int* __restrict__ cnt,
                                               unsigned* __restrict__ perm) {
    __shared__ short zl[64][66];
    const int tid = threadIdx.x;

    if (blockIdx.x >= GEMMB) {
        // ---- edge scatter into fixed-capacity buckets
        const int i64 = probe_i64(srcp);
        const int e = (blockIdx.x - GEMMB) * 256 + tid;
        if (e < N_EDGES) {
            int d = ldi(dstp, i64, e);
            int s = ldi(srcp, i64, e);
            int r = ldi(etp, i64, e);
            int pos = atomicAdd(&cnt[d], 1);
            if (pos < CAP) perm[d * CAP + pos] = ((unsigned)r << 16) | (unsigned)s;
        }
        return;
    }

    const int f32 = probe_f32(feat);
    const int wave = tid >> 6, lane = tid & 63;
    const int quad = lane >> 4, col = lane & 15;
    const int r0 = blockIdx.x * 64;

    // A fragments for 4 row-groups (f32 converted in-register)
    short8 a0g[4], a1g[4];
#pragma unroll
    for (int g = 0; g < 4; ++g) {
        int am = r0 + g * 16 + col;
        if (am >= N_NODES) am = N_NODES - 1;
        if (f32) {
            const float* Af = (const float*)feat;
            float4v f0 = *(const float4v*)(Af + am * F + quad * 8);
            float4v f1 = *(const float4v*)(Af + am * F + quad * 8 + 4);
            float4v g0 = *(const float4v*)(Af + am * F + 32 + quad * 8);
            float4v g1 = *(const float4v*)(Af + am * F + 32 + quad * 8 + 4);
#pragma unroll
            for (int j = 0; j < 4; ++j) {
                a0g[g][j] = f2bs(f0[j]); a0g[g][j + 4] = f2bs(f1[j]);
                a1g[g][j] = f2bs(g0[j]); a1g[g][j + 4] = f2bs(g1[j]);
            }
        } else {
            const __hip_bfloat16* A = (const __hip_bfloat16*)feat;
            a0g[g] = *(const short8*)(A + am * F + quad * 8);
            a1g[g] = *(const short8*)(A + am * F + 32 + quad * 8);
        }
    }

    const short8* Wp = (const short8*)Wpack;

    // ---- zc tile (t = 20 + wave): W loaded once, 4 row-groups
    {
        const int t = 20 + wave;
        short8 b0 = Wp[(t * 2 + 0) * 64 + lane];
        short8 b1 = Wp[(t * 2 + 1) * 64 + lane];
        const int cb = wave * 16 + quad * 4;
#pragma unroll
        for (int g = 0; g < 4; ++g) {
            float4v acc = {0.f, 0.f, 0.f, 0.f};
            acc = __builtin_amdgcn_mfma_f32_16x16x32_bf16(b0, a0g[g], acc, 0, 0, 0);
            acc = __builtin_amdgcn_mfma_f32_16x16x32_bf16(b1, a1g[g], acc, 0, 0, 0);
            short4v pv;
#pragma unroll
            for (int j = 0; j < 4; ++j) pv[j] = f2bs(acc[j]);
            const int row = r0 + g * 16 + col;
            *(short4v*)(zc + row * F + cb) = pv;
            *(short4v*)&zl[g * 16 + col][cb] = pv;
        }
    }
    __syncthreads();

    // ---- GEMM2 A-side (zc^T): zl[m][k]
    short8 c0g[4], c1g[4];
#pragma unroll
    for (int g = 0; g < 4; ++g) {
        c0g[g] = *(const short8*)&zl[g * 16 + col][quad * 8];
        c1g[g] = *(const short8*)&zl[g * 16 + col][32 + quad * 8];
    }

    // ---- selfz tiles (t = wave*5 .. +4): W once, 4 groups
#pragma unroll
    for (int tt = 0; tt < 5; ++tt) {
        const int t = wave * 5 + tt;
        short8 b0 = Wp[(t * 2 + 0) * 64 + lane];
        short8 b1 = Wp[(t * 2 + 1) * 64 + lane];
#pragma unroll
        for (int g = 0; g < 4; ++g) {
            float4v acc = {0.f, 0.f, 0.f, 0.f};
            acc = __builtin_amdgcn_mfma_f32_16x16x32_bf16(b0, a0g[g], acc, 0, 0, 0);
            acc = __builtin_amdgcn_mfma_f32_16x16x32_bf16(b1, a1g[g], acc, 0, 0, 0);
            short4v pv;
#pragma unroll
            for (int j = 0; j < 4; ++j) pv[j] = f2bs(acc[j]);
            const int row = r0 + g * 16 + col;
            *(short4v*)(selfz + row * HF + t * 16 + quad * 4) = pv;
        }
    }

    // ---- GEMM2 tiles -> a_src (quads 0,1) / a_dst (quads 2,3)
    const short8* W2p = (const short8*)W2pack;
    __hip_bfloat16* dsta = (quad & 2) ? a_dst : a_src;
    const int hoff = (quad & 1) * 4;
#pragma unroll
    for (int tt = 0; tt < 5; ++tt) {
        const int t = wave * 5 + tt;
        short8 b0 = W2p[(t * 2 + 0) * 64 + lane];
        short8 b1 = W2p[(t * 2 + 1) * 64 + lane];
#pragma unroll
        for (int g = 0; g < 4; ++g) {
            float4v acc = {0.f, 0.f, 0.f, 0.f};
            acc = __builtin_amdgcn_mfma_f32_16x16x32_bf16(b0, c0g[g], acc, 0, 0, 0);
            acc = __builtin_amdgcn_mfma_f32_16x16x32_bf16(b1, c1g[g], acc, 0, 0, 0);
            short4v pv;
#pragma unroll
            for (int j = 0; j < 4; ++j) pv[j] = f2bs(acc[j]);
            const int row = r0 + g * 16 + col;
            *(short4v*)(dsta + row * 160 + t * 8 + hoff) = pv;
        }
    }
}

// ---------------- K4: one wave per dst. Two phases:
//  A) lane e (< n) computes the 5 leaky-relu logits ONCE for edge e, stores
//     {att0..4, src_bits} into an 8-float LDS row
//  B) 64 feature-lanes accumulate: 2 broadcast ds_reads + 1 coalesced zc gather
//     + 5 FMAs per edge.
__global__ __launch_bounds__(256) void k4_agg(const void* __restrict__ feat_raw,
                                              const __hip_bfloat16* __restrict__ selfz,
                                              const unsigned short* __restrict__ zc,
                                              const __hip_bfloat16* __restrict__ a_src,
                                              const __hip_bfloat16* __restrict__ a_dst,
                                              const int* __restrict__ cnt,
                                              const unsigned* __restrict__ perm,
                                              void* __restrict__ out) {
    __shared__ short sdv[4][160];
    __shared__ float satt[4][CAP][8];   // {att0..att4, src_bits, pad, pad}
    const int f32 = probe_f32(feat_raw);
    const int tid = threadIdx.x;
    const int wid = tid >> 6, lane = tid & 63;
    const int d = blockIdx.x * 4 + wid;       // 6250*4 = 25000

    if (lane < 20)
        *(short8*)&sdv[wid][lane * 8] = *(const short8*)((const short*)a_dst + d * 160 + lane * 8);
    const unsigned pk = perm[d * CAP + lane];
    const int s_l = (int)(pk & 0xFFFFu), r_l = (int)(pk >> 16);
    int n = cnt[d];
    if (n > CAP) n = CAP;
    __syncthreads();

    const short* as = (const short*)a_src;

    // ---- phase A: per-edge attention, one lane per edge
    if (lane < n) {
        short8 sv = *(const short8*)(as + s_l * 160 + r_l * 8);
        short8 dv = *(const short8*)&sdv[wid][r_l * 8];
        float av[H];
#pragma unroll
        for (int h = 0; h < H; ++h) {
            float t = b2f((unsigned short)sv[h]) + b2f((unsigned short)dv[h]);
            av[h] = fmaxf(t, 0.01f * t);
        }
        float4v w0 = {av[0], av[1], av[2], av[3]};
        *(float4v*)&satt[wid][lane][0] = w0;
        float2v w1 = {av[4], __int_as_float(s_l)};
        *(float2v*)&satt[wid][lane][4] = w1;
    }
    __syncthreads();

    // ---- phase B: accumulate over edges (4-deep unrolled)
    float acc[H] = {0.f, 0.f, 0.f, 0.f, 0.f};
    int e = 0;
    for (; e + 4 <= n; e += 4) {
        float4v A[4]; float2v Bv[4];
#pragma unroll
        for (int u = 0; u < 4; ++u) {
            A[u] = *(const float4v*)&satt[wid][e + u][0];
            Bv[u] = *(const float2v*)&satt[wid][e + u][4];
        }
        float zs[4];
#pragma unroll
        for (int u = 0; u < 4; ++u)
            zs[u] = b2f(zc[__float_as_int(Bv[u][1]) * F + lane]);
#pragma unroll
        for (int u = 0; u < 4; ++u) {
            acc[0] += A[u][0] * zs[u];
            acc[1] += A[u][1] * zs[u];
            acc[2] += A[u][2] * zs[u];
            acc[3] += A[u][3] * zs[u];
            acc[4] += Bv[u][0] * zs[u];
        }
    }
    for (; e < n; ++e) {
        float4v A = *(const float4v*)&satt[wid][e][0];
        float2v Bv = *(const float2v*)&satt[wid][e][4];
        float zs = b2f(zc[__float_as_int(Bv[1]) * F + lane]);
        acc[0] += A[0] * zs; acc[1] += A[1] * zs; acc[2] += A[2] * zs;
        acc[3] += A[3] * zs; acc[4] += Bv[0] * zs;
    }

    const int ob = d * HF + lane;
    if (f32) {
        float* o = (float*)out;
#pragma unroll
        for (int h = 0; h < H; ++h)
            o[ob + h * F] = acc[h] + __bfloat162float(selfz[ob + h * F]);
    } else {
        __hip_bfloat16* o = (__hip_bfloat16*)out;
#pragma unroll
        for (int h = 0; h < H; ++h)
            o[ob + h * F] = __float2bfloat16(acc[h] + __bfloat162float(selfz[ob + h * F]));
    }
}

extern "C" void kernel_launch(void* const* d_in, const int* in_sizes, int n_in,
                              void* d_out, int out_size, void* d_ws, size_t ws_size,
                              hipStream_t stream) {
    const void* feat = d_in[0];
    const void* src  = d_in[1];
    const void* dst  = d_in[2];
    const void* et   = d_in[3];
    const void* fcw  = d_in[4];
    const void* sfw  = d_in[5];
    const void* aw   = d_in[6];
    const void* wc   = d_in[7];

    // ws (~42 MB): selfz | zc | a_src | a_dst | Wpack | W2pack | perm | cnt
    char* w = (char*)d_ws;
    __hip_bfloat16* selfz  = (__hip_bfloat16*)w;  w += (size_t)MPAD * HF * 2;
    __hip_bfloat16* zc     = (__hip_bfloat16*)w;  w += (size_t)MPAD * F * 2;
    __hip_bfloat16* a_src  = (__hip_bfloat16*)w;  w += (size_t)MPAD * 160 * 2;
    __hip_bfloat16* a_dst  = (__hip_bfloat16*)w;  w += (size_t)MPAD * 160 * 2;
    __hip_bfloat16* Wpack  = (__hip_bfloat16*)w;  w += 24576 * 2;
    __hip_bfloat16* W2pack = (__hip_bfloat16*)w;  w += 20480 * 2;
    unsigned* perm = (unsigned*)w;                w += (size_t)N_NODES * CAP * 4;
    int* cnt       = (int*)w;

    // 3 dispatches total: pack+zero -> gemm||scatter -> aggregate
    k0_setup<<<176 + (N_NODES + 255) / 256, 256, 0, stream>>>(feat, fcw, sfw, aw, wc,
                                                              Wpack, W2pack, cnt);
    k2_gemm<<<GEMMB + (N_EDGES + 255) / 256, 256, 0, stream>>>(feat, src, dst, et,
                                                               Wpack, W2pack, selfz, zc,
                                                               a_src, a_dst, cnt, perm);
    k4_agg<<<N_NODES / 4, 256, 0, stream>>>(feat, selfz, (const unsigned short*)zc,
                                            a_src, a_dst, cnt, perm, d_out);
}